// Round 8
// baseline (60.306 us; speedup 1.0000x reference)
//
#include <hip/hip_runtime.h>

namespace {
constexpr int Bn = 32, Dn = 64, Hn = 64, Wn = 64;
constexpr int PLANE = Hn * Wn;   // 4096
constexpr int NW  = 8;           // waves per block, splitting d
constexpr int DPW = Dn / NW;     // 8 d-slices per wave
constexpr float SCALE = 0.125f;  // 64^-0.5
typedef float f4a __attribute__((ext_vector_type(4), aligned(4)));
}

__global__ __launch_bounds__(512, 8) void dilate_attn_kernel(
    const float* __restrict__ q, const float* __restrict__ k,
    const float* __restrict__ v, float* __restrict__ out)
{
    __shared__ float2 red[NW][9][64];   // 36864 B; 4 blocks/CU = 147 KB

    const int t  = threadIdx.x;
    const int l  = t & 63;
    const int wv = t >> 6;              // wave id -> d-eighth
    const int ci = l & 31;              // lane col-pair index
    const int lr = l >> 5;              // row within stripe
    const int c  = ci * 2;              // first of this lane's 2 pixel cols

    // XCD-chunked swizzle: 1024 blocks -> 128 contiguous (b,stripe) per XCD
    const int bid = blockIdx.x;
    const int swz = (bid & 7) * 128 + (bid >> 3);
    const int b      = swz >> 5;
    const int stripe = swz & 31;
    const int hr     = stripe * 2 + lr; // this lane's pixel row

    const int  base = b * Dn * PLANE;
    const bool ci0 = (ci == 0), ci31 = (ci == 31);
    const int  cb = ci0 ? 0 : (ci31 ? (c - 2) : (c - 1));

    int  koff[3];
    bool rok[3];
#pragma unroll
    for (int di = 0; di < 3; ++di) {
        const int kr = hr - 1 + di;
        rok[di] = (kr >= 0) && (kr < Hn);
        const int krc = min(max(kr, 0), Hn - 1);   // clamped: always in-bounds
        koff[di] = krc * Wn + cb;
    }
    const int qoff = hr * Wn + c;

    float a0[9], a1[9];
#pragma unroll
    for (int n = 0; n < 9; ++n) { a0[n] = 0.0f; a1[n] = 0.0f; }

    // -------- Phase 1: partial scores over this wave's 8 d-slices ----------
    {
        const float* kp = k + base + wv * DPW * PLANE;
        const float* qp = q + base + wv * DPW * PLANE;
#pragma unroll
        for (int ds = 0; ds < DPW; ++ds) {
            const f4a r0 = *(const f4a*)(kp + ds * PLANE + koff[0]);
            const f4a r1 = *(const f4a*)(kp + ds * PLANE + koff[1]);
            const f4a r2 = *(const f4a*)(kp + ds * PLANE + koff[2]);
            const float2 qv = *(const float2*)(qp + ds * PLANE + qoff);
#pragma unroll
            for (int di = 0; di < 3; ++di) {
                const f4a vv = (di == 0) ? r0 : (di == 1) ? r1 : r2;
                const float w0 = ci31 ? vv.y : vv.x;
                const float w1 = ci0 ? vv.x : (ci31 ? vv.z : vv.y);
                const float w2 = ci0 ? vv.y : (ci31 ? vv.w : vv.z);
                const float w3 = ci0 ? vv.z : vv.w;
                a0[di * 3 + 0] = fmaf(qv.x, w0, a0[di * 3 + 0]);
                a0[di * 3 + 1] = fmaf(qv.x, w1, a0[di * 3 + 1]);
                a0[di * 3 + 2] = fmaf(qv.x, w2, a0[di * 3 + 2]);
                a1[di * 3 + 0] = fmaf(qv.y, w1, a1[di * 3 + 0]);
                a1[di * 3 + 1] = fmaf(qv.y, w2, a1[di * 3 + 1]);
                a1[di * 3 + 2] = fmaf(qv.y, w3, a1[di * 3 + 2]);
            }
        }
    }

    // -------- prefetch v iter-0 BEFORE the reduction/softmax section --------
    const float* vp = v + base + wv * DPW * PLANE;
    const f4a pv0 = *(const f4a*)(vp + koff[0]);
    const f4a pv1 = *(const f4a*)(vp + koff[1]);
    const f4a pv2 = *(const f4a*)(vp + koff[2]);

    // -------- cross-wave reduction: wave wv owns window position n=wv ------
#pragma unroll
    for (int n = 0; n < 9; ++n) red[wv][n][l] = make_float2(a0[n], a1[n]);
    __syncthreads();
    {
        float2 s = red[0][wv][l];
#pragma unroll
        for (int sw = 1; sw < NW; ++sw) {
            const float2 p = red[sw][wv][l];
            s.x += p.x; s.y += p.y;
        }
        red[0][wv][l] = s;
        if (wv == NW - 1) {          // wave 7 also reduces n=8
            float2 s8 = red[0][8][l];
#pragma unroll
            for (int sw = 1; sw < NW; ++sw) {
                const float2 p = red[sw][8][l];
                s8.x += p.x; s8.y += p.y;
            }
            red[0][8][l] = s8;
        }
    }
    __syncthreads();
#pragma unroll
    for (int n = 0; n < 9; ++n) {
        const float2 s = red[0][n][l];
        a0[n] = s.x; a1[n] = s.y;
    }

    // -------- zero invalid-position SCORES (reference: q . 0-pad = 0) -------
#pragma unroll
    for (int di = 0; di < 3; ++di)
#pragma unroll
        for (int dj = 0; dj < 3; ++dj) {
            const int n = di * 3 + dj;
            a0[n] = (rok[di] && (dj != 0 || !ci0))  ? a0[n] : 0.0f;
            a1[n] = (rok[di] && (dj != 2 || !ci31)) ? a1[n] : 0.0f;
        }
#pragma unroll
    for (int n = 0; n < 9; ++n) { a0[n] *= SCALE; a1[n] *= SCALE; }
    float m0 = a0[0], m1 = a1[0];
#pragma unroll
    for (int n = 1; n < 9; ++n) { m0 = fmaxf(m0, a0[n]); m1 = fmaxf(m1, a1[n]); }
    float s0 = 0.0f, s1 = 0.0f;
#pragma unroll
    for (int n = 0; n < 9; ++n) {
        a0[n] = __expf(a0[n] - m0); s0 += a0[n];
        a1[n] = __expf(a1[n] - m1); s1 += a1[n];
    }
    const float i0 = 1.0f / s0, i1 = 1.0f / s1;
#pragma unroll
    for (int n = 0; n < 9; ++n) { a0[n] *= i0; a1[n] *= i1; }

    // -------- zero invalid-position WEIGHTS (reference: attn * v=0 there) ---
#pragma unroll
    for (int di = 0; di < 3; ++di)
#pragma unroll
        for (int dj = 0; dj < 3; ++dj) {
            const int n = di * 3 + dj;
            a0[n] = (rok[di] && (dj != 0 || !ci0))  ? a0[n] : 0.0f;
            a1[n] = (rok[di] && (dj != 2 || !ci31)) ? a1[n] : 0.0f;
        }

    // -------- Phase 2: out = attn . v_window for this wave's d-eighth -------
    {
        float* op = out + base + wv * DPW * PLANE;
#pragma unroll
        for (int ds = 0; ds < DPW; ++ds) {
            const f4a r0 = (ds == 0) ? pv0 : *(const f4a*)(vp + ds * PLANE + koff[0]);
            const f4a r1 = (ds == 0) ? pv1 : *(const f4a*)(vp + ds * PLANE + koff[1]);
            const f4a r2 = (ds == 0) ? pv2 : *(const f4a*)(vp + ds * PLANE + koff[2]);
            float o0 = 0.0f, o1 = 0.0f;
#pragma unroll
            for (int di = 0; di < 3; ++di) {
                const f4a vv = (di == 0) ? r0 : (di == 1) ? r1 : r2;
                const float w0 = ci31 ? vv.y : vv.x;
                const float w1 = ci0 ? vv.x : (ci31 ? vv.z : vv.y);
                const float w2 = ci0 ? vv.y : (ci31 ? vv.w : vv.z);
                const float w3 = ci0 ? vv.z : vv.w;
                o0 = fmaf(a0[di * 3 + 0], w0, o0);
                o0 = fmaf(a0[di * 3 + 1], w1, o0);
                o0 = fmaf(a0[di * 3 + 2], w2, o0);
                o1 = fmaf(a1[di * 3 + 0], w1, o1);
                o1 = fmaf(a1[di * 3 + 1], w2, o1);
                o1 = fmaf(a1[di * 3 + 2], w3, o1);
            }
            *(float2*)(op + ds * PLANE + qoff) = make_float2(o0, o1);
        }
    }
}

extern "C" void kernel_launch(void* const* d_in, const int* in_sizes, int n_in,
                              void* d_out, int out_size, void* d_ws, size_t ws_size,
                              hipStream_t stream) {
    const float* q = (const float*)d_in[0];
    const float* k = (const float*)d_in[1];
    const float* v = (const float*)d_in[2];
    float* out = (float*)d_out;
    (void)in_sizes; (void)n_in; (void)out_size; (void)d_ws; (void)ws_size;

    const int grid = Bn * 32;  // 1024 blocks x 512 thr -> 4/CU, 32 waves/CU
    dilate_attn_kernel<<<grid, 512, 0, stream>>>(q, k, v, out);
}

// Round 9
// 46.850 us; speedup vs baseline: 1.2872x; 1.2872x over previous
//
#include <hip/hip_runtime.h>

namespace {
constexpr int Bn = 32, Dn = 64, Hn = 64, Wn = 64;
constexpr int PLANE = Hn * Wn;   // 4096
constexpr int NW  = 8;           // waves per block, splitting d
constexpr int DPW = Dn / NW;     // 8 d-slices per wave
constexpr float SCALE = 0.125f;  // 64^-0.5
typedef float f4a __attribute__((ext_vector_type(4), aligned(4)));
}

__global__ __launch_bounds__(512, 8) void dilate_attn_kernel(
    const float* __restrict__ q, const float* __restrict__ k,
    const float* __restrict__ v, float* __restrict__ out)
{
    __shared__ float2 red[NW][9][64];   // 36864 B; 4 blocks/CU = 147 KB

    const int t  = threadIdx.x;
    const int l  = t & 63;
    const int wv = t >> 6;              // wave id -> d-eighth
    const int ci = l & 31;              // lane col-pair index
    const int lr = l >> 5;              // row within stripe
    const int c  = ci * 2;              // first of this lane's 2 pixel cols

    // XCD-chunked swizzle: 1024 blocks -> 128 contiguous (b,stripe) per XCD
    const int bid = blockIdx.x;
    const int swz = (bid & 7) * 128 + (bid >> 3);
    const int b      = swz >> 5;
    const int stripe = swz & 31;
    const int hr     = stripe * 2 + lr; // this lane's pixel row

    const int  base = b * Dn * PLANE;
    const bool ci0 = (ci == 0), ci31 = (ci == 31);

    // UNIFORM window base: cols c-1..c+2 for every lane. Edge lanes pull
    // prev/next-row (or prev/next-plane) values into vv.x / vv.w — those
    // positions are exactly the mask-zeroed ones, and all such reads hit
    // valid mapped memory EXCEPT 4B under/overflow at the very first/last
    // plane, handled by the peeled iterations below.
    int  koff[3];
    bool rok[3];
#pragma unroll
    for (int di = 0; di < 3; ++di) {
        const int kr = hr - 1 + di;
        rok[di] = (kr >= 0) && (kr < Hn);
        const int krc = min(max(kr, 0), Hn - 1);
        koff[di] = krc * Wn + (c - 1);   // may be -1 (ci0,row0) or 4093 (ci31,row63)
    }
    const int qoff = hr * Wn + c;

    const bool fix_first = (b == 0)      && (wv == 0);      // wave-uniform
    const bool fix_last  = (b == Bn - 1) && (wv == NW - 1); // wave-uniform

    float a0[9], a1[9];
#pragma unroll
    for (int n = 0; n < 9; ++n) { a0[n] = 0.0f; a1[n] = 0.0f; }

    // accumulate one d-slice: uniform component map, no selects
    auto ACC = [&](const f4a& r0, const f4a& r1, const f4a& r2, const float2 qv) {
#pragma unroll
        for (int di = 0; di < 3; ++di) {
            const f4a vv = (di == 0) ? r0 : (di == 1) ? r1 : r2;
            a0[di * 3 + 0] = fmaf(qv.x, vv.x, a0[di * 3 + 0]);
            a0[di * 3 + 1] = fmaf(qv.x, vv.y, a0[di * 3 + 1]);
            a0[di * 3 + 2] = fmaf(qv.x, vv.z, a0[di * 3 + 2]);
            a1[di * 3 + 0] = fmaf(qv.y, vv.y, a1[di * 3 + 0]);
            a1[di * 3 + 1] = fmaf(qv.y, vv.z, a1[di * 3 + 1]);
            a1[di * 3 + 2] = fmaf(qv.y, vv.w, a1[di * 3 + 2]);
        }
    };
    // safe load for the global-first plane: clamp to >=0, shift right if clamped
    auto LDF = [&](const float* p, int off) -> f4a {
        const f4a tv = *(const f4a*)(p + max(off, 0));
        f4a sh; sh.x = 0.0f; sh.y = tv.x; sh.z = tv.y; sh.w = tv.z;
        return (off < 0) ? sh : tv;
    };
    // safe load for the global-last plane: clamp to <=PLANE-4, shift left
    auto LDL = [&](const float* p, int off) -> f4a {
        const f4a tv = *(const f4a*)(p + min(off, PLANE - 4));
        f4a sh; sh.x = tv.y; sh.y = tv.z; sh.z = tv.w; sh.w = 0.0f;
        return (off > PLANE - 4) ? sh : tv;
    };

    // -------- Phase 1: partial scores over this wave's 8 d-slices ----------
    {
        const float* kp = k + base + wv * DPW * PLANE;
        const float* qp = q + base + wv * DPW * PLANE;
        {   // ds = 0 (peeled: possible 4B underflow at b==0)
            f4a r0, r1, r2;
            if (fix_first) {
                r0 = LDF(kp, koff[0]); r1 = LDF(kp, koff[1]); r2 = LDF(kp, koff[2]);
            } else {
                r0 = *(const f4a*)(kp + koff[0]);
                r1 = *(const f4a*)(kp + koff[1]);
                r2 = *(const f4a*)(kp + koff[2]);
            }
            const float2 qv = *(const float2*)(qp + qoff);
            ACC(r0, r1, r2, qv);
            kp += PLANE; qp += PLANE;
        }
#pragma unroll 3
        for (int ds = 1; ds < DPW - 1; ++ds) {
            const f4a r0 = *(const f4a*)(kp + koff[0]);
            const f4a r1 = *(const f4a*)(kp + koff[1]);
            const f4a r2 = *(const f4a*)(kp + koff[2]);
            const float2 qv = *(const float2*)(qp + qoff);
            kp += PLANE; qp += PLANE;
            ACC(r0, r1, r2, qv);
        }
        {   // ds = DPW-1 (peeled: possible 4B overflow at b==Bn-1)
            f4a r0, r1, r2;
            if (fix_last) {
                r0 = LDL(kp, koff[0]); r1 = LDL(kp, koff[1]); r2 = LDL(kp, koff[2]);
            } else {
                r0 = *(const f4a*)(kp + koff[0]);
                r1 = *(const f4a*)(kp + koff[1]);
                r2 = *(const f4a*)(kp + koff[2]);
            }
            const float2 qv = *(const float2*)(qp + qoff);
            ACC(r0, r1, r2, qv);
        }
    }

    // -------- prefetch v ds=0 before the reduction/softmax wall -------------
    const float* vp = v + base + wv * DPW * PLANE;
    f4a pv0, pv1, pv2;
    if (fix_first) {
        pv0 = LDF(vp, koff[0]); pv1 = LDF(vp, koff[1]); pv2 = LDF(vp, koff[2]);
    } else {
        pv0 = *(const f4a*)(vp + koff[0]);
        pv1 = *(const f4a*)(vp + koff[1]);
        pv2 = *(const f4a*)(vp + koff[2]);
    }

    // -------- cross-wave reduction: wave wv owns window position n=wv ------
#pragma unroll
    for (int n = 0; n < 9; ++n) red[wv][n][l] = make_float2(a0[n], a1[n]);
    __syncthreads();
    {
        float2 s = red[0][wv][l];
#pragma unroll
        for (int sw = 1; sw < NW; ++sw) {
            const float2 p = red[sw][wv][l];
            s.x += p.x; s.y += p.y;
        }
        red[0][wv][l] = s;
        if (wv == NW - 1) {          // wave 7 also reduces n=8
            float2 s8 = red[0][8][l];
#pragma unroll
            for (int sw = 1; sw < NW; ++sw) {
                const float2 p = red[sw][8][l];
                s8.x += p.x; s8.y += p.y;
            }
            red[0][8][l] = s8;
        }
    }
    __syncthreads();
#pragma unroll
    for (int n = 0; n < 9; ++n) {
        const float2 s = red[0][n][l];
        a0[n] = s.x; a1[n] = s.y;
    }

    // -------- zero invalid-position SCORES (reference: q . 0-pad = 0) -------
#pragma unroll
    for (int di = 0; di < 3; ++di)
#pragma unroll
        for (int dj = 0; dj < 3; ++dj) {
            const int n = di * 3 + dj;
            a0[n] = (rok[di] && (dj != 0 || !ci0))  ? a0[n] : 0.0f;
            a1[n] = (rok[di] && (dj != 2 || !ci31)) ? a1[n] : 0.0f;
        }
#pragma unroll
    for (int n = 0; n < 9; ++n) { a0[n] *= SCALE; a1[n] *= SCALE; }
    float m0 = a0[0], m1 = a1[0];
#pragma unroll
    for (int n = 1; n < 9; ++n) { m0 = fmaxf(m0, a0[n]); m1 = fmaxf(m1, a1[n]); }
    float s0 = 0.0f, s1 = 0.0f;
#pragma unroll
    for (int n = 0; n < 9; ++n) {
        a0[n] = __expf(a0[n] - m0); s0 += a0[n];
        a1[n] = __expf(a1[n] - m1); s1 += a1[n];
    }
    const float i0 = 1.0f / s0, i1 = 1.0f / s1;
#pragma unroll
    for (int n = 0; n < 9; ++n) { a0[n] *= i0; a1[n] *= i1; }

    // -------- zero invalid-position WEIGHTS (reference: attn * v=0 there) ---
#pragma unroll
    for (int di = 0; di < 3; ++di)
#pragma unroll
        for (int dj = 0; dj < 3; ++dj) {
            const int n = di * 3 + dj;
            a0[n] = (rok[di] && (dj != 0 || !ci0))  ? a0[n] : 0.0f;
            a1[n] = (rok[di] && (dj != 2 || !ci31)) ? a1[n] : 0.0f;
        }

    auto PV = [&](const f4a& r0, const f4a& r1, const f4a& r2) -> float2 {
        float o0 = 0.0f, o1 = 0.0f;
#pragma unroll
        for (int di = 0; di < 3; ++di) {
            const f4a vv = (di == 0) ? r0 : (di == 1) ? r1 : r2;
            o0 = fmaf(a0[di * 3 + 0], vv.x, o0);
            o0 = fmaf(a0[di * 3 + 1], vv.y, o0);
            o0 = fmaf(a0[di * 3 + 2], vv.z, o0);
            o1 = fmaf(a1[di * 3 + 0], vv.y, o1);
            o1 = fmaf(a1[di * 3 + 1], vv.z, o1);
            o1 = fmaf(a1[di * 3 + 2], vv.w, o1);
        }
        return make_float2(o0, o1);
    };

    // -------- Phase 2: out = attn . v_window for this wave's d-eighth -------
    {
        float* op = out + base + wv * DPW * PLANE;
        {   // ds = 0 uses the prefetched values
            *(float2*)(op + qoff) = PV(pv0, pv1, pv2);
            vp += PLANE; op += PLANE;
        }
#pragma unroll 3
        for (int ds = 1; ds < DPW - 1; ++ds) {
            const f4a r0 = *(const f4a*)(vp + koff[0]);
            const f4a r1 = *(const f4a*)(vp + koff[1]);
            const f4a r2 = *(const f4a*)(vp + koff[2]);
            vp += PLANE;
            *(float2*)(op + qoff) = PV(r0, r1, r2);
            op += PLANE;
        }
        {   // ds = DPW-1 (peeled: possible 4B overflow at b==Bn-1)
            f4a r0, r1, r2;
            if (fix_last) {
                r0 = LDL(vp, koff[0]); r1 = LDL(vp, koff[1]); r2 = LDL(vp, koff[2]);
            } else {
                r0 = *(const f4a*)(vp + koff[0]);
                r1 = *(const f4a*)(vp + koff[1]);
                r2 = *(const f4a*)(vp + koff[2]);
            }
            *(float2*)(op + qoff) = PV(r0, r1, r2);
        }
    }
}

extern "C" void kernel_launch(void* const* d_in, const int* in_sizes, int n_in,
                              void* d_out, int out_size, void* d_ws, size_t ws_size,
                              hipStream_t stream) {
    const float* q = (const float*)d_in[0];
    const float* k = (const float*)d_in[1];
    const float* v = (const float*)d_in[2];
    float* out = (float*)d_out;
    (void)in_sizes; (void)n_in; (void)out_size; (void)d_ws; (void)ws_size;

    const int grid = Bn * 32;  // 1024 blocks x 512 thr -> 4/CU, 32 waves/CU
    dilate_attn_kernel<<<grid, 512, 0, stream>>>(q, k, v, out);
}

// Round 10
// 33.197 us; speedup vs baseline: 1.8166x; 1.4113x over previous
//
#include <hip/hip_runtime.h>

namespace {
constexpr int Bn = 32, Dn = 64, Hn = 64, Wn = 64;
constexpr int PLANE = Hn * Wn;   // 4096
constexpr int NW  = 8;           // waves per block, splitting d
constexpr int DPW = Dn / NW;     // 8 d-slices per wave
constexpr float SCALE = 0.125f;  // 64^-0.5
typedef float f4a __attribute__((ext_vector_type(4), aligned(4)));
}

__global__ __launch_bounds__(512, 6) void dilate_attn_kernel(
    const float* __restrict__ q, const float* __restrict__ k,
    const float* __restrict__ v, float* __restrict__ out)
{
    __shared__ float2 red[NW][9][64];   // 36864 B; 3 blocks/CU = 110 KB

    const int t  = threadIdx.x;
    const int l  = t & 63;
    const int wv = t >> 6;              // wave id -> d-eighth
    const int ci = l & 31;              // lane col-pair index
    const int lr = l >> 5;              // row within stripe
    const int c  = ci * 2;              // first of this lane's 2 pixel cols

    // XCD-chunked swizzle: 1024 blocks -> 128 contiguous (b,stripe) per XCD
    const int bid = blockIdx.x;
    const int swz = (bid & 7) * 128 + (bid >> 3);
    const int b      = swz >> 5;
    const int stripe = swz & 31;
    const int hr     = stripe * 2 + lr; // this lane's pixel row

    const int  base = b * Dn * PLANE;
    const bool ci0 = (ci == 0), ci31 = (ci == 31);

    // UNIFORM window base: cols c-1..c+2 for every lane; no per-component
    // selects. Edge lanes pull prev/next-row (or prev/next-plane) values
    // into vv.x / vv.w — exactly the mask-zeroed positions. All such reads
    // hit valid mapped memory EXCEPT a 4B underflow at the global-first
    // plane and a 4B overflow at the global-last plane (peeled below).
    int  koff[3];
    bool rok[3];
#pragma unroll
    for (int di = 0; di < 3; ++di) {
        const int kr = hr - 1 + di;
        rok[di] = (kr >= 0) && (kr < Hn);
        const int krc = min(max(kr, 0), Hn - 1);
        koff[di] = krc * Wn + (c - 1);   // may be -1 or 4093
    }
    const int qoff = hr * Wn + c;

    const bool fix_first = (b == 0)      && (wv == 0);      // wave-uniform
    const bool fix_last  = (b == Bn - 1) && (wv == NW - 1); // wave-uniform

    float a0[9], a1[9];
#pragma unroll
    for (int n = 0; n < 9; ++n) { a0[n] = 0.0f; a1[n] = 0.0f; }

    // accumulate one d-slice: uniform component map, no selects
    auto ACC = [&](const f4a& r0, const f4a& r1, const f4a& r2, const float2 qv) {
#pragma unroll
        for (int di = 0; di < 3; ++di) {
            const f4a vv = (di == 0) ? r0 : (di == 1) ? r1 : r2;
            a0[di * 3 + 0] = fmaf(qv.x, vv.x, a0[di * 3 + 0]);
            a0[di * 3 + 1] = fmaf(qv.x, vv.y, a0[di * 3 + 1]);
            a0[di * 3 + 2] = fmaf(qv.x, vv.z, a0[di * 3 + 2]);
            a1[di * 3 + 0] = fmaf(qv.y, vv.y, a1[di * 3 + 0]);
            a1[di * 3 + 1] = fmaf(qv.y, vv.z, a1[di * 3 + 1]);
            a1[di * 3 + 2] = fmaf(qv.y, vv.w, a1[di * 3 + 2]);
        }
    };
    // safe load, global-first plane: clamp to >=0, shift right if clamped
    auto LDF = [&](const float* p, int off) -> f4a {
        const f4a tv = *(const f4a*)(p + max(off, 0));
        f4a sh; sh.x = 0.0f; sh.y = tv.x; sh.z = tv.y; sh.w = tv.z;
        return (off < 0) ? sh : tv;
    };
    // safe load, global-last plane: clamp to <=PLANE-4, shift left
    auto LDL = [&](const float* p, int off) -> f4a {
        const f4a tv = *(const f4a*)(p + min(off, PLANE - 4));
        f4a sh; sh.x = tv.y; sh.y = tv.z; sh.z = tv.w; sh.w = 0.0f;
        return (off > PLANE - 4) ? sh : tv;
    };

    // -------- Phase 1: partial scores over this wave's 8 d-slices ----------
    {
        const float* kp = k + base + wv * DPW * PLANE;
        const float* qp = q + base + wv * DPW * PLANE;
        {   // ds = 0 (peeled: possible 4B underflow at b==0)
            f4a r0, r1, r2;
            if (fix_first) {
                r0 = LDF(kp, koff[0]); r1 = LDF(kp, koff[1]); r2 = LDF(kp, koff[2]);
            } else {
                r0 = *(const f4a*)(kp + koff[0]);
                r1 = *(const f4a*)(kp + koff[1]);
                r2 = *(const f4a*)(kp + koff[2]);
            }
            const float2 qv = *(const float2*)(qp + qoff);
            ACC(r0, r1, r2, qv);
            kp += PLANE; qp += PLANE;
        }
#pragma unroll 3
        for (int ds = 1; ds < DPW - 1; ++ds) {
            const f4a r0 = *(const f4a*)(kp + koff[0]);
            const f4a r1 = *(const f4a*)(kp + koff[1]);
            const f4a r2 = *(const f4a*)(kp + koff[2]);
            const float2 qv = *(const float2*)(qp + qoff);
            kp += PLANE; qp += PLANE;
            ACC(r0, r1, r2, qv);
        }
        {   // ds = DPW-1 (peeled: possible 4B overflow at b==Bn-1)
            f4a r0, r1, r2;
            if (fix_last) {
                r0 = LDL(kp, koff[0]); r1 = LDL(kp, koff[1]); r2 = LDL(kp, koff[2]);
            } else {
                r0 = *(const f4a*)(kp + koff[0]);
                r1 = *(const f4a*)(kp + koff[1]);
                r2 = *(const f4a*)(kp + koff[2]);
            }
            const float2 qv = *(const float2*)(qp + qoff);
            ACC(r0, r1, r2, qv);
        }
    }

    // -------- prefetch v ds=0 before the reduction/softmax wall -------------
    const float* vp = v + base + wv * DPW * PLANE;
    f4a pv0, pv1, pv2;
    if (fix_first) {
        pv0 = LDF(vp, koff[0]); pv1 = LDF(vp, koff[1]); pv2 = LDF(vp, koff[2]);
    } else {
        pv0 = *(const f4a*)(vp + koff[0]);
        pv1 = *(const f4a*)(vp + koff[1]);
        pv2 = *(const f4a*)(vp + koff[2]);
    }

    // -------- cross-wave reduction: wave wv owns window position n=wv ------
#pragma unroll
    for (int n = 0; n < 9; ++n) red[wv][n][l] = make_float2(a0[n], a1[n]);
    __syncthreads();
    {
        float2 s = red[0][wv][l];
#pragma unroll
        for (int sw = 1; sw < NW; ++sw) {
            const float2 p = red[sw][wv][l];
            s.x += p.x; s.y += p.y;
        }
        red[0][wv][l] = s;
        if (wv == NW - 1) {          // wave 7 also reduces n=8
            float2 s8 = red[0][8][l];
#pragma unroll
            for (int sw = 1; sw < NW; ++sw) {
                const float2 p = red[sw][8][l];
                s8.x += p.x; s8.y += p.y;
            }
            red[0][8][l] = s8;
        }
    }
    __syncthreads();
#pragma unroll
    for (int n = 0; n < 9; ++n) {
        const float2 s = red[0][n][l];
        a0[n] = s.x; a1[n] = s.y;
    }

    // -------- zero invalid-position SCORES (reference: q . 0-pad = 0) -------
#pragma unroll
    for (int di = 0; di < 3; ++di)
#pragma unroll
        for (int dj = 0; dj < 3; ++dj) {
            const int n = di * 3 + dj;
            a0[n] = (rok[di] && (dj != 0 || !ci0))  ? a0[n] : 0.0f;
            a1[n] = (rok[di] && (dj != 2 || !ci31)) ? a1[n] : 0.0f;
        }
#pragma unroll
    for (int n = 0; n < 9; ++n) { a0[n] *= SCALE; a1[n] *= SCALE; }
    float m0 = a0[0], m1 = a1[0];
#pragma unroll
    for (int n = 1; n < 9; ++n) { m0 = fmaxf(m0, a0[n]); m1 = fmaxf(m1, a1[n]); }
    float s0 = 0.0f, s1 = 0.0f;
#pragma unroll
    for (int n = 0; n < 9; ++n) {
        a0[n] = __expf(a0[n] - m0); s0 += a0[n];
        a1[n] = __expf(a1[n] - m1); s1 += a1[n];
    }
    const float i0 = 1.0f / s0, i1 = 1.0f / s1;
#pragma unroll
    for (int n = 0; n < 9; ++n) { a0[n] *= i0; a1[n] *= i1; }

    // -------- zero invalid-position WEIGHTS (reference: attn * v=0 there) ---
#pragma unroll
    for (int di = 0; di < 3; ++di)
#pragma unroll
        for (int dj = 0; dj < 3; ++dj) {
            const int n = di * 3 + dj;
            a0[n] = (rok[di] && (dj != 0 || !ci0))  ? a0[n] : 0.0f;
            a1[n] = (rok[di] && (dj != 2 || !ci31)) ? a1[n] : 0.0f;
        }

    auto PV = [&](const f4a& r0, const f4a& r1, const f4a& r2) -> float2 {
        float o0 = 0.0f, o1 = 0.0f;
#pragma unroll
        for (int di = 0; di < 3; ++di) {
            const f4a vv = (di == 0) ? r0 : (di == 1) ? r1 : r2;
            o0 = fmaf(a0[di * 3 + 0], vv.x, o0);
            o0 = fmaf(a0[di * 3 + 1], vv.y, o0);
            o0 = fmaf(a0[di * 3 + 2], vv.z, o0);
            o1 = fmaf(a1[di * 3 + 0], vv.y, o1);
            o1 = fmaf(a1[di * 3 + 1], vv.z, o1);
            o1 = fmaf(a1[di * 3 + 2], vv.w, o1);
        }
        return make_float2(o0, o1);
    };

    // -------- Phase 2: out = attn . v_window for this wave's d-eighth -------
    {
        float* op = out + base + wv * DPW * PLANE;
        {   // ds = 0 uses the prefetched values
            *(float2*)(op + qoff) = PV(pv0, pv1, pv2);
            vp += PLANE; op += PLANE;
        }
#pragma unroll 3
        for (int ds = 1; ds < DPW - 1; ++ds) {
            const f4a r0 = *(const f4a*)(vp + koff[0]);
            const f4a r1 = *(const f4a*)(vp + koff[1]);
            const f4a r2 = *(const f4a*)(vp + koff[2]);
            vp += PLANE;
            *(float2*)(op + qoff) = PV(r0, r1, r2);
            op += PLANE;
        }
        {   // ds = DPW-1 (peeled: possible 4B overflow at b==Bn-1)
            f4a r0, r1, r2;
            if (fix_last) {
                r0 = LDL(vp, koff[0]); r1 = LDL(vp, koff[1]); r2 = LDL(vp, koff[2]);
            } else {
                r0 = *(const f4a*)(vp + koff[0]);
                r1 = *(const f4a*)(vp + koff[1]);
                r2 = *(const f4a*)(vp + koff[2]);
            }
            *(float2*)(op + qoff) = PV(r0, r1, r2);
        }
    }
}

extern "C" void kernel_launch(void* const* d_in, const int* in_sizes, int n_in,
                              void* d_out, int out_size, void* d_ws, size_t ws_size,
                              hipStream_t stream) {
    const float* q = (const float*)d_in[0];
    const float* k = (const float*)d_in[1];
    const float* v = (const float*)d_in[2];
    float* out = (float*)d_out;
    (void)in_sizes; (void)n_in; (void)out_size; (void)d_ws; (void)ws_size;

    const int grid = Bn * 32;  // 1024 blocks x 512 thr; 3 blocks/CU resident
    dilate_attn_kernel<<<grid, 512, 0, stream>>>(q, k, v, out);
}